// Round 4
// baseline (151.975 us; speedup 1.0000x reference)
//
#include <hip/hip_runtime.h>

typedef __attribute__((ext_vector_type(8))) short short8;   // 8 bf16 = 4 VGPRs
typedef __attribute__((ext_vector_type(4))) float floatx4;  // MFMA acc

typedef __attribute__((address_space(3))) unsigned int lds_u32;
typedef __attribute__((address_space(1))) const unsigned int glb_u32;

static __device__ __forceinline__ unsigned short f2bf(float f) {
    unsigned int u = __float_as_uint(f);
    return (unsigned short)((u + 0x7FFFu + ((u >> 16) & 1u)) >> 16);   // RNE
}
// async 16-B global->LDS DMA; LDS dest = wave-uniform base + lane*16
static __device__ __forceinline__ void cp16(const ushort* g, ushort* l) {
    __builtin_amdgcn_global_load_lds((glb_u32*)g, (lds_u32*)l, 16, 0, 0);
}

// ---- prep: x->bf16 padded (4112) + weight repack (1536). NO gather here:
// same-stream kernels serialize, so gather must live inside the conv grids
// to overlap. Weights repacked MFMA-fragment-linear [12][4][8][512] so a conv
// wave's B-fragment load is ONE contiguous 1KB global load (L2-hot).
__global__ __launch_bounds__(256)
void prep_kernel(const float* __restrict__ x,
                 const float* __restrict__ w1, const float* __restrict__ w2,
                 ushort* __restrict__ xb, ushort* __restrict__ h1b,
                 ushort* __restrict__ w1q, ushort* __restrict__ w2q)
{
    const int blk = blockIdx.x, tid = threadIdx.x;
    if (blk < 4112) {
        // ---------- x -> bf16 padded [B][514][256]; zero pads in xb AND h1b ----------
        const int r = blk * 4 + (tid >> 6);
        const int c = (tid & 63) * 4;
        const int b = r / 514, tp = r % 514;
        ushort4 o;
        if (tp >= 1 && tp <= 512) {
            float4 v = *(const float4*)(x + ((size_t)(b * 512 + tp - 1) * 256 + c));
            o.x = f2bf(v.x); o.y = f2bf(v.y); o.z = f2bf(v.z); o.w = f2bf(v.w);
        } else {
            o.x = o.y = o.z = o.w = 0;
            *(ushort4*)(h1b + (size_t)r * 256 + c) = o;   // zero h1b pad rows
        }
        *(ushort4*)(xb + (size_t)r * 256 + c) = o;
    } else {
        // ---------- weights [F][C][3] -> fragment-linear [12][4][8][512] ----------
        const bool second = blk >= 4880;
        const int e = (blk - (second ? 4880 : 4112)) * 256 + tid;
        const float* w = second ? w2 : w1;
        ushort* wq = second ? w2q : w1q;
        const int f = e / 768, j = e % 768;
        const int c = j & 255, kr = j >> 8;
        const int se = kr * 4 + (c >> 6);              // K-step 0..11
        const int kk = c & 63;                         // k within step
        const int wg = f >> 6, ni = (f >> 4) & 3, colf = f & 15;
        const int kh = kk >> 5, qk = (kk >> 3) & 3, jj = kk & 7;
        wq[(size_t)se * 16384 + wg * 4096 + (ni * 2 + kh) * 512
           + (qk * 16 + colf) * 8 + jj] = f2bf(w[f * 768 + c * 3 + kr]);
    }
}

// ---- conv1d(K=3) MFMA GEMM + interleaved gather blocks ----
// Grid 1088 = 64 groups of 17: 8 conv + 9 gather. The write-BW-bound gather
// (64 out rows/block) co-resides with the latency-bound conv on every CU, so
// the 74 MB of output writes hide under conv latency. Conv: A via tiny 2x4KB
// LDS dbuf (cp16, quad-swizzled, ONE barrier/step); B direct-global
// fragment-linear (contiguous 1KB wave loads, L2-resident). ~12.5 KB LDS ->
// 3 blocks/CU.  gbase: conv1 handles gather ids [0,576), conv2 [576,1152).
template<bool IS_CONV2>
__global__ __launch_bounds__(256, 3)
void conv_mfma_kernel(const ushort* __restrict__ src,  // [B][514][256] bf16 padded
                      const ushort* __restrict__ wq,   // [12][4][8][512] bf16 frags
                      const float* __restrict__ cbias,
                      const float* __restrict__ gamma, const float* __restrict__ beta,
                      const float* __restrict__ lw, const float* __restrict__ lb,
                      ushort* __restrict__ outb,       // conv1: h1b
                      float* __restrict__ durp,        // conv2: [B][512]
                      const float* __restrict__ x,     // gather path
                      const int* __restrict__ target,
                      float* __restrict__ out0,        // [B][2304][256]
                      int gbase)
{
    __shared__ ushort As[2][2048];                     // 2 x 4KB, quad-swizzled
    __shared__ float sum_s[4][32], sq_s[4][32], mu_s[32], rs_s[32];
    __shared__ int cum[512], ps[256], sidx[64];        // gather path only

    const int tid = threadIdx.x;
    const int grp = blockIdx.x / 17, rmod = blockIdx.x % 17;

    if (rmod >= 8) {
        // ---------- gather: 64 output rows per block ----------
        const int bg = gbase + grp * 9 + (rmod - 8);
        const int b = bg / 36, t0o = (bg % 36) * 64;
        const int v0 = target[b * 512 + 2 * tid];
        const int v1 = target[b * 512 + 2 * tid + 1];
        ps[tid] = v0 + v1;
        __syncthreads();
        for (int off = 1; off < 256; off <<= 1) {
            int t = (tid >= off) ? ps[tid - off] : 0;
            __syncthreads();
            ps[tid] += t;
            __syncthreads();
        }
        const int excl = tid ? ps[tid - 1] : 0;
        cum[2 * tid]     = excl + v0;
        cum[2 * tid + 1] = excl + v0 + v1;
        __syncthreads();
        const int total = cum[511];
        if (tid < 64) {
            int t = t0o + tid;
            int lo = 0, hi = 512;
            while (lo < hi) {
                int mid = (lo + hi) >> 1;
                if (cum[mid] <= t) lo = mid + 1; else hi = mid;
            }
            sidx[tid] = (t < total) ? ((lo < 512) ? lo : 511) : -1;
        }
        __syncthreads();
        const float4* x4 = (const float4*)x;
        float4* o4 = (float4*)out0;
        const int lane6 = tid & 63, g4 = tid >> 6;
        #pragma unroll 4
        for (int rr = 0; rr < 16; ++rr) {
            int r = rr * 4 + g4;
            int idx = sidx[r];
            float4 v = make_float4(0.f, 0.f, 0.f, 0.f);
            if (idx >= 0) v = x4[((size_t)(b * 512 + idx)) * 64 + lane6];
            o4[((size_t)(b * 2304 + t0o + r)) * 64 + lane6] = v;
        }
        return;
    }
    const int conv_id = grp * 8 + rmod;                // [0,512)

    // ---------- conv path ----------
    const int w_ = tid >> 6, lane = tid & 63;
    const int q = lane >> 4, col = lane & 15;
    const int b  = conv_id & 31;                       // XCD-local batches
    const int t0 = (conv_id >> 5) << 5;
    const int rot = conv_id % 12;                      // K-step stagger

    floatx4 acc[2][4] = {};
    const int arow = tid >> 3, aquad = (tid & 7) ^ (arow & 7);
    const ushort* xbb = src + (size_t)b * 514 * 256;
    const ushort* bptr = wq + (size_t)w_ * 4096 + lane * 8;

    auto se_of = [&](int s) { int v = s + rot; return v >= 12 ? v - 12 : v; };
#define STAGE_A(SE_, BUF_) do {                                                   \
        const int se_ = (SE_);                                                    \
        const int krow_ = se_ >> 2, cbo_ = (se_ & 3) << 6;                        \
        cp16(xbb + (size_t)(t0 + krow_ + arow) * 256 + cbo_ + aquad * 8,          \
             &As[BUF_][0] + w_ * 512);                                            \
    } while (0)

    STAGE_A(se_of(0), 0);
    __syncthreads();

    int cur = 0;
    #pragma unroll
    for (int s = 0; s < 12; ++s) {
        const int nb = cur ^ 1;
        if (s + 1 < 12) STAGE_A(se_of(s + 1), nb);     // issue next-step DMA first
        const int se = se_of(s);
        short8 bf[4][2], af[2][2];
        #pragma unroll
        for (int ni = 0; ni < 4; ++ni)                 // B: contiguous 1KB wave loads
            #pragma unroll
            for (int kh = 0; kh < 2; ++kh)
                bf[ni][kh] = *(const short8*)(bptr + (size_t)se * 16384 + (ni * 2 + kh) * 512);
        #pragma unroll
        for (int mi = 0; mi < 2; ++mi)                 // A: swizzled LDS reads
            #pragma unroll
            for (int kh = 0; kh < 2; ++kh)
                af[mi][kh] = *(const short8*)((const char*)&As[cur][0]
                    + (mi * 16 + col) * 128 + (((kh * 4 + q) ^ (col & 7)) * 16));
        #pragma unroll
        for (int kh = 0; kh < 2; ++kh)
            #pragma unroll
            for (int mi = 0; mi < 2; ++mi)
                #pragma unroll
                for (int ni = 0; ni < 4; ++ni)
                    acc[mi][ni] = __builtin_amdgcn_mfma_f32_16x16x32_bf16(
                        af[mi][kh], bf[ni][kh], acc[mi][ni], 0, 0, 0);
        __syncthreads();                               // one barrier per step
        cur = nb;
    }
#undef STAGE_A

    // ---- epilogue: bias + per-row LN stats from registers ----
    const int base_c = w_ * 64;
    float cb4[4], gm4[4], bt4[4];
    #pragma unroll
    for (int ni = 0; ni < 4; ++ni) {
        cb4[ni] = cbias[base_c + ni * 16 + col];
        gm4[ni] = gamma[base_c + ni * 16 + col];
        bt4[ni] = beta [base_c + ni * 16 + col];
    }
    float rsum[2][4] = {}, rsq[2][4] = {};
    #pragma unroll
    for (int mi = 0; mi < 2; ++mi)
        #pragma unroll
        for (int ni = 0; ni < 4; ++ni)
            #pragma unroll
            for (int r = 0; r < 4; ++r) {
                float v = acc[mi][ni][r] + cb4[ni];
                acc[mi][ni][r] = v;
                rsum[mi][r] += v;
                rsq [mi][r] += v * v;
            }
    #pragma unroll
    for (int mi = 0; mi < 2; ++mi)
        #pragma unroll
        for (int r = 0; r < 4; ++r) {
            float s = rsum[mi][r], ss = rsq[mi][r];
            #pragma unroll
            for (int d = 8; d > 0; d >>= 1) {
                s  += __shfl_down(s,  d, 16);
                ss += __shfl_down(ss, d, 16);
            }
            if (col == 0) {
                sum_s[w_][mi * 16 + q * 4 + r] = s;
                sq_s [w_][mi * 16 + q * 4 + r] = ss;
            }
        }
    __syncthreads();
    if (tid < 32) {
        float s  = sum_s[0][tid] + sum_s[1][tid] + sum_s[2][tid] + sum_s[3][tid];
        float ss = sq_s [0][tid] + sq_s [1][tid] + sq_s [2][tid] + sq_s [3][tid];
        float mu = s * (1.f / 256.f);
        mu_s[tid] = mu;
        rs_s[tid] = rsqrtf(ss * (1.f / 256.f) - mu * mu + 1e-5f);
    }
    __syncthreads();

    if (!IS_CONV2) {
        #pragma unroll
        for (int mi = 0; mi < 2; ++mi)
            #pragma unroll
            for (int ni = 0; ni < 4; ++ni)
                #pragma unroll
                for (int r = 0; r < 4; ++r) {
                    int row = mi * 16 + q * 4 + r;
                    float v = (acc[mi][ni][r] - mu_s[row]) * rs_s[row] * gm4[ni] + bt4[ni];
                    outb[((size_t)b * 514 + t0 + row + 1) * 256 + base_c + ni * 16 + col]
                        = f2bf(fmaxf(v, 0.f));
                }
    } else {
        float lw4[4];
        #pragma unroll
        for (int ni = 0; ni < 4; ++ni) lw4[ni] = lw[base_c + ni * 16 + col];
        float dsum[2][4] = {};
        #pragma unroll
        for (int mi = 0; mi < 2; ++mi)
            #pragma unroll
            for (int ni = 0; ni < 4; ++ni)
                #pragma unroll
                for (int r = 0; r < 4; ++r) {
                    int row = mi * 16 + q * 4 + r;
                    float v = (acc[mi][ni][r] - mu_s[row]) * rs_s[row] * gm4[ni] + bt4[ni];
                    dsum[mi][r] += fmaxf(v, 0.f) * lw4[ni];
                }
        #pragma unroll
        for (int mi = 0; mi < 2; ++mi)
            #pragma unroll
            for (int r = 0; r < 4; ++r) {
                float s = dsum[mi][r];
                #pragma unroll
                for (int d = 8; d > 0; d >>= 1) s += __shfl_down(s, d, 16);
                if (col == 0) sum_s[w_][mi * 16 + q * 4 + r] = s;
            }
        __syncthreads();
        if (tid < 32)
            durp[b * 512 + t0 + tid] = fmaxf(sum_s[0][tid] + sum_s[1][tid]
                                           + sum_s[2][tid] + sum_s[3][tid] + lb[0], 0.f);
    }
}

extern "C" void kernel_launch(void* const* d_in, const int* in_sizes, int n_in,
                              void* d_out, int out_size, void* d_ws, size_t ws_size,
                              hipStream_t stream) {
    const float* x      = (const float*)d_in[0];
    const int*   target = (const int*)  d_in[1];
    const float* c1w = (const float*)d_in[3];
    const float* c1b = (const float*)d_in[4];
    const float* g1  = (const float*)d_in[5];
    const float* b1  = (const float*)d_in[6];
    const float* c2w = (const float*)d_in[7];
    const float* c2b = (const float*)d_in[8];
    const float* g2  = (const float*)d_in[9];
    const float* b2  = (const float*)d_in[10];
    const float* lw  = (const float*)d_in[11];
    const float* lb  = (const float*)d_in[12];

    const size_t PADEL = (size_t)32 * 514 * 256;
    ushort* xb   = (ushort*)d_ws;                 // [32][514][256] bf16 padded
    ushort* h1b  = xb + PADEL;                    // [32][514][256] bf16 padded
    ushort* w1q  = h1b + PADEL;                   // [12][4][8][512]
    ushort* w2q  = w1q + 196608;

    float* out0 = (float*)d_out;                  // [32, 2304, 256]
    float* durp = out0 + (size_t)32 * 2304 * 256; // [32, 512]

    prep_kernel<<<5648, 256, 0, stream>>>(x, c1w, c2w, xb, h1b, w1q, w2q);
    conv_mfma_kernel<false><<<1088, 256, 0, stream>>>(
        xb, w1q, c1b, g1, b1, nullptr, nullptr, h1b, nullptr,
        x, target, out0, 0);
    conv_mfma_kernel<true><<<1088, 256, 0, stream>>>(
        h1b, w2q, c2b, g2, b2, lw, lb, nullptr, durp,
        x, target, out0, 576);
}

// Round 5
// 150.739 us; speedup vs baseline: 1.0082x; 1.0082x over previous
//
#include <hip/hip_runtime.h>

typedef __attribute__((ext_vector_type(8))) short short8;   // 8 bf16 = 4 VGPRs
typedef __attribute__((ext_vector_type(4))) float floatx4;  // MFMA acc
typedef __attribute__((ext_vector_type(4))) float f4v;      // vector float4

typedef __attribute__((address_space(3))) unsigned int lds_u32;
typedef __attribute__((address_space(1))) const unsigned int glb_u32;

static __device__ __forceinline__ unsigned short f2bf(float f) {
    unsigned int u = __float_as_uint(f);
    return (unsigned short)((u + 0x7FFFu + ((u >> 16) & 1u)) >> 16);   // RNE
}
// async 16-B global->LDS DMA; LDS dest = wave-uniform base + lane*16
static __device__ __forceinline__ void cp16(const ushort* g, ushort* l) {
    __builtin_amdgcn_global_load_lds((glb_u32*)g, (lds_u32*)l, 16, 0, 0);
}

// Row-swizzle: padded row tp stores logical 16B-chunk ch at chunk ch^(tp&7).
// prep writes xb swizzled, conv1 writes h1b swizzled; conv slab-stage copies
// rows verbatim (linear cp16) and ds_read applies the same XOR -> conflict-free.

// ---- prep: x->bf16 swizzled (4112) + weight repack (1536) + cumsum (32) ----
__global__ __launch_bounds__(256)
void prep_kernel(const float* __restrict__ x, const int* __restrict__ target,
                 const float* __restrict__ w1, const float* __restrict__ w2,
                 ushort* __restrict__ xb, ushort* __restrict__ h1b,
                 ushort* __restrict__ w1q, ushort* __restrict__ w2q,
                 int* __restrict__ cumg)
{
    __shared__ int ps[256];
    const int blk = blockIdx.x, tid = threadIdx.x;
    if (blk < 4112) {
        // ---------- x -> bf16 swizzled padded [B][514][256]; zero pads in xb AND h1b ----------
        const int r = blk * 4 + (tid >> 6);
        const int c = (tid & 63) * 4;
        const int b = r / 514, tp = r % 514;
        const int e2 = ((((c >> 3) ^ (tp & 7)) << 3) | (c & 7));   // swizzled elem pos
        ushort4 o;
        if (tp >= 1 && tp <= 512) {
            float4 v = *(const float4*)(x + ((size_t)(b * 512 + tp - 1) * 256 + c));
            o.x = f2bf(v.x); o.y = f2bf(v.y); o.z = f2bf(v.z); o.w = f2bf(v.w);
        } else {
            o.x = o.y = o.z = o.w = 0;
            *(ushort4*)(h1b + (size_t)r * 256 + e2) = o;   // zero h1b pad rows
        }
        *(ushort4*)(xb + (size_t)r * 256 + e2) = o;
    } else if (blk < 5648) {
        // ---------- weights [F][C][3] -> fragment-linear [12][4][8][512] ----------
        const bool second = blk >= 4880;
        const int e = (blk - (second ? 4880 : 4112)) * 256 + tid;
        const float* w = second ? w2 : w1;
        ushort* wq = second ? w2q : w1q;
        const int f = e / 768, j = e % 768;
        const int c = j & 255, kr = j >> 8;
        const int se = kr * 4 + (c >> 6);              // K-step 0..11
        const int kk = c & 63;                         // k within step
        const int wg = f >> 6, ni = (f >> 4) & 3, colf = f & 15;
        const int kh = kk >> 5, qk = (kk >> 3) & 3, jj = kk & 7;
        wq[(size_t)se * 16384 + wg * 4096 + (ni * 2 + kh) * 512
           + (qk * 16 + colf) * 8 + jj] = f2bf(w[f * 768 + c * 3 + kr]);
    } else {
        // ---------- per-batch cumsum of target (once, not per gather block) ----------
        const int b = blk - 5648;
        const int v0 = target[b * 512 + 2 * tid];
        const int v1 = target[b * 512 + 2 * tid + 1];
        ps[tid] = v0 + v1;
        __syncthreads();
        for (int off = 1; off < 256; off <<= 1) {
            int t = (tid >= off) ? ps[tid - off] : 0;
            __syncthreads();
            ps[tid] += t;
            __syncthreads();
        }
        const int excl = tid ? ps[tid - 1] : 0;
        cumg[b * 512 + 2 * tid]     = excl + v0;
        cumg[b * 512 + 2 * tid + 1] = excl + v0 + v1;
    }
}

// ---- conv1d(K=3) MFMA GEMM: stage A-slab ONCE, then barrier-free K-loop ----
// Slab = 36 swizzled rows x 512B (18KB) via linear cp16; ONE __syncthreads;
// then 12 steps of {8 contiguous 1KB B wave-loads (L2) + 4 swizzled
// ds_read_b128 + 16 MFMA} with NO barriers -> compiler software-pipelines
// with counted vmcnt. Gather blocks (9 per 17) use precomputed cumsum and
// nontemporal stores (no RFO on the 75MB out0 stream).
template<bool IS_CONV2>
__global__ __launch_bounds__(256, 3)
void conv_mfma_kernel(const ushort* __restrict__ src,  // [B][514][256] bf16 swizzled
                      const ushort* __restrict__ wq,   // [12][4][8][512] bf16 frags
                      const float* __restrict__ cbias,
                      const float* __restrict__ gamma, const float* __restrict__ beta,
                      const float* __restrict__ lw, const float* __restrict__ lb,
                      ushort* __restrict__ outb,       // conv1: h1b (swizzled)
                      float* __restrict__ durp,        // conv2: [B][512]
                      const float* __restrict__ x,     // gather path
                      const int* __restrict__ cumg,    // [B][512] cumsum
                      float* __restrict__ out0,        // [B][2304][256]
                      int gbase)
{
    __shared__ ushort slab[36 * 256];                  // 18KB swizzled A-slab
    __shared__ float sum_s[4][32], sq_s[4][32], mu_s[32], rs_s[32];
    __shared__ int cum_s[512], sidx[64];               // gather path only

    const int tid = threadIdx.x;
    const int grp = blockIdx.x / 17, rmod = blockIdx.x % 17;

    if (rmod >= 8) {
        // ---------- gather: 64 output rows per block, scan precomputed ----------
        const int bg = gbase + grp * 9 + (rmod - 8);
        const int b = bg / 36, t0o = (bg % 36) * 64;
        cum_s[tid]       = cumg[b * 512 + tid];
        cum_s[tid + 256] = cumg[b * 512 + 256 + tid];
        __syncthreads();
        const int total = cum_s[511];
        if (tid < 64) {
            int t = t0o + tid;
            int lo = 0, hi = 512;
            while (lo < hi) {
                int mid = (lo + hi) >> 1;
                if (cum_s[mid] <= t) lo = mid + 1; else hi = mid;
            }
            sidx[tid] = (t < total) ? ((lo < 512) ? lo : 511) : -1;
        }
        __syncthreads();
        const f4v* x4 = (const f4v*)x;
        f4v* o4 = (f4v*)out0;
        const int lane6 = tid & 63, g4 = tid >> 6;
        #pragma unroll 4
        for (int rr = 0; rr < 16; ++rr) {
            int r = rr * 4 + g4;
            int idx = sidx[r];
            f4v v = {0.f, 0.f, 0.f, 0.f};
            if (idx >= 0) v = x4[((size_t)(b * 512 + idx)) * 64 + lane6];
            __builtin_nontemporal_store(v, &o4[((size_t)(b * 2304 + t0o + r)) * 64 + lane6]);
        }
        return;
    }
    const int conv_id = grp * 8 + rmod;                // [0,512)

    // ---------- conv path ----------
    const int w_ = tid >> 6, lane = tid & 63;
    const int q = lane >> 4, col = lane & 15;
    const int b  = conv_id & 31;                       // XCD-local batches
    const int t0 = (conv_id >> 5) << 5;
    const int rot = conv_id % 12;                      // K-step stagger

    const ushort* xbb = src + (size_t)b * 514 * 256;
    // stage 36 rows (t0 .. t0+35), rows 34/35 are harmless overread pad
    #pragma unroll
    for (int r = 0; r < 4; ++r) {
        const int i = r * 8 + w_ * 2 + (lane >> 5);
        cp16(xbb + (size_t)(t0 + i) * 256 + (lane & 31) * 8,
             slab + r * 2048 + w_ * 512);
    }
    if (w_ < 2) {
        const int i = 32 + w_ * 2 + (lane >> 5);
        cp16(xbb + (size_t)(t0 + i) * 256 + (lane & 31) * 8,
             slab + 8192 + w_ * 512);
    }
    __syncthreads();                                   // ONLY barrier before epilogue

    floatx4 acc[2][4] = {};
    const ushort* bptr = wq + (size_t)w_ * 4096 + lane * 8;
    #pragma unroll
    for (int s = 0; s < 12; ++s) {
        int se = s + rot; if (se >= 12) se -= 12;
        const int krow = se >> 2, cb8 = (se & 3) << 3; // chunk base (16B units)
        short8 bf[4][2], af[2][2];
        #pragma unroll
        for (int ni = 0; ni < 4; ++ni)                 // B: contiguous 1KB wave loads
            #pragma unroll
            for (int kh = 0; kh < 2; ++kh)
                bf[ni][kh] = *(const short8*)(bptr + (size_t)se * 16384 + (ni * 2 + kh) * 512);
        #pragma unroll
        for (int mi = 0; mi < 2; ++mi) {               // A: swizzled slab reads
            #pragma unroll
            for (int kh = 0; kh < 2; ++kh) {
                const int i = krow + mi * 16 + col;
                const int ch = cb8 + kh * 4 + q;
                af[mi][kh] = *(const short8*)(slab + i * 256 + ((ch ^ (i & 7)) << 3));
            }
        }
        #pragma unroll
        for (int kh = 0; kh < 2; ++kh)
            #pragma unroll
            for (int mi = 0; mi < 2; ++mi)
                #pragma unroll
                for (int ni = 0; ni < 4; ++ni)
                    acc[mi][ni] = __builtin_amdgcn_mfma_f32_16x16x32_bf16(
                        af[mi][kh], bf[ni][kh], acc[mi][ni], 0, 0, 0);
    }

    // ---- epilogue: bias + per-row LN stats from registers ----
    const int base_c = w_ * 64;
    float cb4[4], gm4[4], bt4[4];
    #pragma unroll
    for (int ni = 0; ni < 4; ++ni) {
        cb4[ni] = cbias[base_c + ni * 16 + col];
        gm4[ni] = gamma[base_c + ni * 16 + col];
        bt4[ni] = beta [base_c + ni * 16 + col];
    }
    float rsum[2][4] = {}, rsq[2][4] = {};
    #pragma unroll
    for (int mi = 0; mi < 2; ++mi)
        #pragma unroll
        for (int ni = 0; ni < 4; ++ni)
            #pragma unroll
            for (int r = 0; r < 4; ++r) {
                float v = acc[mi][ni][r] + cb4[ni];
                acc[mi][ni][r] = v;
                rsum[mi][r] += v;
                rsq [mi][r] += v * v;
            }
    #pragma unroll
    for (int mi = 0; mi < 2; ++mi)
        #pragma unroll
        for (int r = 0; r < 4; ++r) {
            float s = rsum[mi][r], ss = rsq[mi][r];
            #pragma unroll
            for (int d = 8; d > 0; d >>= 1) {
                s  += __shfl_down(s,  d, 16);
                ss += __shfl_down(ss, d, 16);
            }
            if (col == 0) {
                sum_s[w_][mi * 16 + q * 4 + r] = s;
                sq_s [w_][mi * 16 + q * 4 + r] = ss;
            }
        }
    __syncthreads();
    if (tid < 32) {
        float s  = sum_s[0][tid] + sum_s[1][tid] + sum_s[2][tid] + sum_s[3][tid];
        float ss = sq_s [0][tid] + sq_s [1][tid] + sq_s [2][tid] + sq_s [3][tid];
        float mu = s * (1.f / 256.f);
        mu_s[tid] = mu;
        rs_s[tid] = rsqrtf(ss * (1.f / 256.f) - mu * mu + 1e-5f);
    }
    __syncthreads();

    if (!IS_CONV2) {
        #pragma unroll
        for (int mi = 0; mi < 2; ++mi)
            #pragma unroll
            for (int ni = 0; ni < 4; ++ni)
                #pragma unroll
                for (int r = 0; r < 4; ++r) {
                    int row = mi * 16 + q * 4 + r;
                    float v = (acc[mi][ni][r] - mu_s[row]) * rs_s[row] * gm4[ni] + bt4[ni];
                    const int tp = t0 + row + 1;
                    const int cc = base_c + ni * 16 + col;
                    const int e2 = ((((cc >> 3) ^ (tp & 7)) << 3) | (cc & 7));
                    outb[((size_t)b * 514 + tp) * 256 + e2] = f2bf(fmaxf(v, 0.f));
                }
    } else {
        float lw4[4];
        #pragma unroll
        for (int ni = 0; ni < 4; ++ni) lw4[ni] = lw[base_c + ni * 16 + col];
        float dsum[2][4] = {};
        #pragma unroll
        for (int mi = 0; mi < 2; ++mi)
            #pragma unroll
            for (int ni = 0; ni < 4; ++ni)
                #pragma unroll
                for (int r = 0; r < 4; ++r) {
                    int row = mi * 16 + q * 4 + r;
                    float v = (acc[mi][ni][r] - mu_s[row]) * rs_s[row] * gm4[ni] + bt4[ni];
                    dsum[mi][r] += fmaxf(v, 0.f) * lw4[ni];
                }
        #pragma unroll
        for (int mi = 0; mi < 2; ++mi)
            #pragma unroll
            for (int r = 0; r < 4; ++r) {
                float s = dsum[mi][r];
                #pragma unroll
                for (int d = 8; d > 0; d >>= 1) s += __shfl_down(s, d, 16);
                if (col == 0) sum_s[w_][mi * 16 + q * 4 + r] = s;
            }
        __syncthreads();
        if (tid < 32)
            durp[b * 512 + t0 + tid] = fmaxf(sum_s[0][tid] + sum_s[1][tid]
                                           + sum_s[2][tid] + sum_s[3][tid] + lb[0], 0.f);
    }
}

extern "C" void kernel_launch(void* const* d_in, const int* in_sizes, int n_in,
                              void* d_out, int out_size, void* d_ws, size_t ws_size,
                              hipStream_t stream) {
    const float* x      = (const float*)d_in[0];
    const int*   target = (const int*)  d_in[1];
    const float* c1w = (const float*)d_in[3];
    const float* c1b = (const float*)d_in[4];
    const float* g1  = (const float*)d_in[5];
    const float* b1  = (const float*)d_in[6];
    const float* c2w = (const float*)d_in[7];
    const float* c2b = (const float*)d_in[8];
    const float* g2  = (const float*)d_in[9];
    const float* b2  = (const float*)d_in[10];
    const float* lw  = (const float*)d_in[11];
    const float* lb  = (const float*)d_in[12];

    const size_t PADEL = (size_t)32 * 514 * 256;
    ushort* xb   = (ushort*)d_ws;                 // [32][514][256] bf16 swizzled
    ushort* h1b  = xb + PADEL;                    // [32][514][256] bf16 swizzled
    ushort* w1q  = h1b + PADEL;                   // [12][4][8][512]
    ushort* w2q  = w1q + 196608;
    int*    cumg = (int*)(w2q + 196608);          // [32][512]

    float* out0 = (float*)d_out;                  // [32, 2304, 256]
    float* durp = out0 + (size_t)32 * 2304 * 256; // [32, 512]

    prep_kernel<<<5680, 256, 0, stream>>>(x, target, c1w, c2w, xb, h1b, w1q, w2q, cumg);
    conv_mfma_kernel<false><<<1088, 256, 0, stream>>>(
        xb, w1q, c1b, g1, b1, nullptr, nullptr, h1b, nullptr,
        x, cumg, out0, 0);
    conv_mfma_kernel<true><<<1088, 256, 0, stream>>>(
        h1b, w2q, c2b, g2, b2, lw, lb, nullptr, durp,
        x, cumg, out0, 576);
}

// Round 7
// 149.222 us; speedup vs baseline: 1.0184x; 1.0102x over previous
//
#include <hip/hip_runtime.h>

typedef __attribute__((ext_vector_type(8))) short short8;   // 8 bf16 = 4 VGPRs
typedef __attribute__((ext_vector_type(4))) float floatx4;  // MFMA acc
typedef __attribute__((ext_vector_type(4))) float f4v;      // vector float4

typedef __attribute__((address_space(3))) unsigned int lds_u32;
typedef __attribute__((address_space(1))) const unsigned int glb_u32;

static __device__ __forceinline__ unsigned short f2bf(float f) {
    unsigned int u = __float_as_uint(f);
    return (unsigned short)((u + 0x7FFFu + ((u >> 16) & 1u)) >> 16);   // RNE
}
// async 16-B global->LDS DMA; LDS dest = wave-uniform base + lane*16
static __device__ __forceinline__ void cp16(const ushort* g, ushort* l) {
    __builtin_amdgcn_global_load_lds((glb_u32*)g, (lds_u32*)l, 16, 0, 0);
}

// Row-swizzle: padded row tp stores logical 16B-chunk ch at chunk ch^(tp&7).
// xb/h1b stored swizzled; conv slab-stage copies rows verbatim (linear cp16)
// and ds_read applies the same XOR -> conflict-free (rule #21).

// ---- prep: x->bf16 swizzled (4112) + weight repack (1536) + cumsum (32) ----
__global__ __launch_bounds__(256)
void prep_kernel(const float* __restrict__ x, const int* __restrict__ target,
                 const float* __restrict__ w1, const float* __restrict__ w2,
                 ushort* __restrict__ xb, ushort* __restrict__ h1b,
                 ushort* __restrict__ w1q, ushort* __restrict__ w2q,
                 int* __restrict__ cumg)
{
    __shared__ int ps[256];
    const int blk = blockIdx.x, tid = threadIdx.x;
    if (blk < 4112) {
        // ---------- x -> bf16 swizzled padded [B][514][256]; zero pads in xb AND h1b ----------
        const int r = blk * 4 + (tid >> 6);
        const int c = (tid & 63) * 4;
        const int b = r / 514, tp = r % 514;
        const int e2 = ((((c >> 3) ^ (tp & 7)) << 3) | (c & 7));   // swizzled elem pos
        ushort4 o;
        if (tp >= 1 && tp <= 512) {
            float4 v = *(const float4*)(x + ((size_t)(b * 512 + tp - 1) * 256 + c));
            o.x = f2bf(v.x); o.y = f2bf(v.y); o.z = f2bf(v.z); o.w = f2bf(v.w);
        } else {
            o.x = o.y = o.z = o.w = 0;
            *(ushort4*)(h1b + (size_t)r * 256 + e2) = o;   // zero h1b pad rows
        }
        *(ushort4*)(xb + (size_t)r * 256 + e2) = o;
    } else if (blk < 5648) {
        // ---------- weights [F][C][3] -> fragment-linear [12][4][8][512] ----------
        const bool second = blk >= 4880;
        const int e = (blk - (second ? 4880 : 4112)) * 256 + tid;
        const float* w = second ? w2 : w1;
        ushort* wq = second ? w2q : w1q;
        const int f = e / 768, j = e % 768;
        const int c = j & 255, kr = j >> 8;
        const int se = kr * 4 + (c >> 6);              // K-step 0..11
        const int kk = c & 63;                         // k within step
        const int wg = f >> 6, ni = (f >> 4) & 3, colf = f & 15;
        const int kh = kk >> 5, qk = (kk >> 3) & 3, jj = kk & 7;
        wq[(size_t)se * 16384 + wg * 4096 + (ni * 2 + kh) * 512
           + (qk * 16 + colf) * 8 + jj] = f2bf(w[f * 768 + c * 3 + kr]);
    } else {
        // ---------- per-batch cumsum of target (once, not per gather block) ----------
        const int b = blk - 5648;
        const int v0 = target[b * 512 + 2 * tid];
        const int v1 = target[b * 512 + 2 * tid + 1];
        ps[tid] = v0 + v1;
        __syncthreads();
        for (int off = 1; off < 256; off <<= 1) {
            int t = (tid >= off) ? ps[tid - off] : 0;
            __syncthreads();
            ps[tid] += t;
            __syncthreads();
        }
        const int excl = tid ? ps[tid - 1] : 0;
        cumg[b * 512 + 2 * tid]     = excl + v0;
        cumg[b * 512 + 2 * tid + 1] = excl + v0 + v1;
    }
}

// ---- conv1d(K=3) MFMA GEMM: slab staged once; 24 kh-group K-loop with
// explicit one-group-ahead register double-buffer; __launch_bounds__(256,4)
// -> 4 blocks/CU (16 waves) for TLP latency hiding. Live frags per thread:
// acc 32 + 2x(bf 16 + af 8) = 80 VGPR, fits the 128-cap without spill.
// Gather blocks (9 per 17) use precomputed cumsum + nontemporal stores.
template<bool IS_CONV2>
__global__ __launch_bounds__(256, 4)
void conv_mfma_kernel(const ushort* __restrict__ src,  // [B][514][256] bf16 swizzled
                      const ushort* __restrict__ wq,   // [12][4][8][512] bf16 frags
                      const float* __restrict__ cbias,
                      const float* __restrict__ gamma, const float* __restrict__ beta,
                      const float* __restrict__ lw, const float* __restrict__ lb,
                      ushort* __restrict__ outb,       // conv1: h1b (swizzled)
                      float* __restrict__ durp,        // conv2: [B][512]
                      const float* __restrict__ x,     // gather path
                      const int* __restrict__ cumg,    // [B][512] cumsum
                      float* __restrict__ out0,        // [B][2304][256]
                      int gbase)
{
    __shared__ ushort slab[36 * 256];                  // 18KB swizzled A-slab
    __shared__ float sum_s[4][32], sq_s[4][32], mu_s[32], rs_s[32];
    __shared__ int cum_s[512], sidx[64];               // gather path only

    const int tid = threadIdx.x;
    const int grp = blockIdx.x / 17, rmod = blockIdx.x % 17;

    if (rmod >= 8) {
        // ---------- gather: 64 output rows per block, scan precomputed ----------
        const int bg = gbase + grp * 9 + (rmod - 8);
        const int b = bg / 36, t0o = (bg % 36) * 64;
        cum_s[tid]       = cumg[b * 512 + tid];
        cum_s[tid + 256] = cumg[b * 512 + 256 + tid];
        __syncthreads();
        const int total = cum_s[511];
        if (tid < 64) {
            int t = t0o + tid;
            int lo = 0, hi = 512;
            while (lo < hi) {
                int mid = (lo + hi) >> 1;
                if (cum_s[mid] <= t) lo = mid + 1; else hi = mid;
            }
            sidx[tid] = (t < total) ? ((lo < 512) ? lo : 511) : -1;
        }
        __syncthreads();
        const f4v* x4 = (const f4v*)x;
        f4v* o4 = (f4v*)out0;
        const int lane6 = tid & 63, g4 = tid >> 6;
        #pragma unroll 4
        for (int rr = 0; rr < 16; ++rr) {
            int r = rr * 4 + g4;
            int idx = sidx[r];
            f4v v = {0.f, 0.f, 0.f, 0.f};
            if (idx >= 0) v = x4[((size_t)(b * 512 + idx)) * 64 + lane6];
            __builtin_nontemporal_store(v, &o4[((size_t)(b * 2304 + t0o + r)) * 64 + lane6]);
        }
        return;
    }
    const int conv_id = grp * 8 + rmod;                // [0,512)

    // ---------- conv path ----------
    const int w_ = tid >> 6, lane = tid & 63;
    const int q = lane >> 4, col = lane & 15;
    const int b  = conv_id & 31;                       // XCD-local batches
    const int t0 = (conv_id >> 5) << 5;
    const int rot = conv_id % 12;                      // K-step stagger

    const ushort* xbb = src + (size_t)b * 514 * 256;
    // stage 36 rows (t0 .. t0+35); rows 34/35 harmless overread pad
    #pragma unroll
    for (int r = 0; r < 4; ++r) {
        const int i = r * 8 + w_ * 2 + (lane >> 5);
        cp16(xbb + (size_t)(t0 + i) * 256 + (lane & 31) * 8,
             slab + r * 2048 + w_ * 512);
    }
    if (w_ < 2) {
        const int i = 32 + w_ * 2 + (lane >> 5);
        cp16(xbb + (size_t)(t0 + i) * 256 + (lane & 31) * 8,
             slab + 8192 + w_ * 512);
    }
    __syncthreads();                                   // only barrier pre-epilogue

    floatx4 acc[2][4] = {};
    const ushort* bptr = wq + (size_t)w_ * 4096 + lane * 8;

    // 24 kh-groups: g -> (s = g>>1, kh = g&1), se = (s+rot)%12.
    // Explicit 1-group-ahead register dbuf; full unroll => all indices static.
    short8 bf[2][4], af[2][2];
    {
        const int se = rot;
        const int krow = se >> 2, cb8 = (se & 3) << 3;
        #pragma unroll
        for (int ni = 0; ni < 4; ++ni)
            bf[0][ni] = *(const short8*)(bptr + (size_t)se * 16384 + (ni * 2 + 0) * 512);
        #pragma unroll
        for (int mi = 0; mi < 2; ++mi) {
            const int i = krow + mi * 16 + col;
            const int ch = cb8 + 0 * 4 + q;
            af[0][mi] = *(const short8*)(slab + i * 256 + ((ch ^ (i & 7)) << 3));
        }
    }
    #pragma unroll
    for (int g = 0; g < 24; ++g) {
        const int P = g & 1, Nx = P ^ 1;
        if (g + 1 < 24) {                              // issue next group's loads
            const int s1 = (g + 1) >> 1, kh1 = (g + 1) & 1;
            int se1 = s1 + rot; if (se1 >= 12) se1 -= 12;
            const int krow1 = se1 >> 2, cb81 = (se1 & 3) << 3;
            #pragma unroll
            for (int ni = 0; ni < 4; ++ni)
                bf[Nx][ni] = *(const short8*)(bptr + (size_t)se1 * 16384 + (ni * 2 + kh1) * 512);
            #pragma unroll
            for (int mi = 0; mi < 2; ++mi) {
                const int i = krow1 + mi * 16 + col;
                const int ch = cb81 + kh1 * 4 + q;
                af[Nx][mi] = *(const short8*)(slab + i * 256 + ((ch ^ (i & 7)) << 3));
            }
        }
        #pragma unroll
        for (int mi = 0; mi < 2; ++mi)                 // compute current group
            #pragma unroll
            for (int ni = 0; ni < 4; ++ni)
                acc[mi][ni] = __builtin_amdgcn_mfma_f32_16x16x32_bf16(
                    af[P][mi], bf[P][ni], acc[mi][ni], 0, 0, 0);
    }

    // ---- epilogue: bias + per-row LN stats from registers ----
    const int base_c = w_ * 64;
    float cb4[4], gm4[4], bt4[4];
    #pragma unroll
    for (int ni = 0; ni < 4; ++ni) {
        cb4[ni] = cbias[base_c + ni * 16 + col];
        gm4[ni] = gamma[base_c + ni * 16 + col];
        bt4[ni] = beta [base_c + ni * 16 + col];
    }
    float rsum[2][4] = {}, rsq[2][4] = {};
    #pragma unroll
    for (int mi = 0; mi < 2; ++mi)
        #pragma unroll
        for (int ni = 0; ni < 4; ++ni)
            #pragma unroll
            for (int r = 0; r < 4; ++r) {
                float v = acc[mi][ni][r] + cb4[ni];
                acc[mi][ni][r] = v;
                rsum[mi][r] += v;
                rsq [mi][r] += v * v;
            }
    #pragma unroll
    for (int mi = 0; mi < 2; ++mi)
        #pragma unroll
        for (int r = 0; r < 4; ++r) {
            float s = rsum[mi][r], ss = rsq[mi][r];
            #pragma unroll
            for (int d = 8; d > 0; d >>= 1) {
                s  += __shfl_down(s,  d, 16);
                ss += __shfl_down(ss, d, 16);
            }
            if (col == 0) {
                sum_s[w_][mi * 16 + q * 4 + r] = s;
                sq_s [w_][mi * 16 + q * 4 + r] = ss;
            }
        }
    __syncthreads();
    if (tid < 32) {
        float s  = sum_s[0][tid] + sum_s[1][tid] + sum_s[2][tid] + sum_s[3][tid];
        float ss = sq_s [0][tid] + sq_s [1][tid] + sq_s [2][tid] + sq_s [3][tid];
        float mu = s * (1.f / 256.f);
        mu_s[tid] = mu;
        rs_s[tid] = rsqrtf(ss * (1.f / 256.f) - mu * mu + 1e-5f);
    }
    __syncthreads();

    if (!IS_CONV2) {
        #pragma unroll
        for (int mi = 0; mi < 2; ++mi)
            #pragma unroll
            for (int ni = 0; ni < 4; ++ni)
                #pragma unroll
                for (int r = 0; r < 4; ++r) {
                    int row = mi * 16 + q * 4 + r;
                    float v = (acc[mi][ni][r] - mu_s[row]) * rs_s[row] * gm4[ni] + bt4[ni];
                    const int tp = t0 + row + 1;
                    const int cc = base_c + ni * 16 + col;
                    const int e2 = ((((cc >> 3) ^ (tp & 7)) << 3) | (cc & 7));
                    outb[((size_t)b * 514 + tp) * 256 + e2] = f2bf(fmaxf(v, 0.f));
                }
    } else {
        float lw4[4];
        #pragma unroll
        for (int ni = 0; ni < 4; ++ni) lw4[ni] = lw[base_c + ni * 16 + col];
        float dsum[2][4] = {};
        #pragma unroll
        for (int mi = 0; mi < 2; ++mi)
            #pragma unroll
            for (int ni = 0; ni < 4; ++ni)
                #pragma unroll
                for (int r = 0; r < 4; ++r) {
                    int row = mi * 16 + q * 4 + r;
                    float v = (acc[mi][ni][r] - mu_s[row]) * rs_s[row] * gm4[ni] + bt4[ni];
                    dsum[mi][r] += fmaxf(v, 0.f) * lw4[ni];
                }
        #pragma unroll
        for (int mi = 0; mi < 2; ++mi)
            #pragma unroll
            for (int r = 0; r < 4; ++r) {
                float s = dsum[mi][r];
                #pragma unroll
                for (int d = 8; d > 0; d >>= 1) s += __shfl_down(s, d, 16);
                if (col == 0) sum_s[w_][mi * 16 + q * 4 + r] = s;
            }
        __syncthreads();
        if (tid < 32)
            durp[b * 512 + t0 + tid] = fmaxf(sum_s[0][tid] + sum_s[1][tid]
                                           + sum_s[2][tid] + sum_s[3][tid] + lb[0], 0.f);
    }
}

extern "C" void kernel_launch(void* const* d_in, const int* in_sizes, int n_in,
                              void* d_out, int out_size, void* d_ws, size_t ws_size,
                              hipStream_t stream) {
    const float* x      = (const float*)d_in[0];
    const int*   target = (const int*)  d_in[1];
    const float* c1w = (const float*)d_in[3];
    const float* c1b = (const float*)d_in[4];
    const float* g1  = (const float*)d_in[5];
    const float* b1  = (const float*)d_in[6];
    const float* c2w = (const float*)d_in[7];
    const float* c2b = (const float*)d_in[8];
    const float* g2  = (const float*)d_in[9];
    const float* b2  = (const float*)d_in[10];
    const float* lw  = (const float*)d_in[11];
    const float* lb  = (const float*)d_in[12];

    const size_t PADEL = (size_t)32 * 514 * 256;
    ushort* xb   = (ushort*)d_ws;                 // [32][514][256] bf16 swizzled
    ushort* h1b  = xb + PADEL;                    // [32][514][256] bf16 swizzled
    ushort* w1q  = h1b + PADEL;                   // [12][4][8][512]
    ushort* w2q  = w1q + 196608;
    int*    cumg = (int*)(w2q + 196608);          // [32][512]

    float* out0 = (float*)d_out;                  // [32, 2304, 256]
    float* durp = out0 + (size_t)32 * 2304 * 256; // [32, 512]

    prep_kernel<<<5680, 256, 0, stream>>>(x, target, c1w, c2w, xb, h1b, w1q, w2q, cumg);
    conv_mfma_kernel<false><<<1088, 256, 0, stream>>>(
        xb, w1q, c1b, g1, b1, nullptr, nullptr, h1b, nullptr,
        x, cumg, out0, 0);
    conv_mfma_kernel<true><<<1088, 256, 0, stream>>>(
        h1b, w2q, c2b, g2, b2, lw, lb, nullptr, durp,
        x, cumg, out0, 576);
}